// Round 2
// baseline (2133.290 us; speedup 1.0000x reference)
//
#include <hip/hip_runtime.h>
#include <hip/hip_bf16.h>

typedef unsigned short u16;

#define B_ 4
#define C_ 128
#define T_ 1000
#define F_ 65
#define H_ 4
#define E_ 8
#define DH_ 32
#define TP_ 199
#define TC_ 398
#define DQK 520      // E*F
#define DV 2080      // DH*F
#define EPS 1e-5f

__device__ __forceinline__ float bf2f(u16 u) {
    union { float f; unsigned int i; } v; v.i = ((unsigned int)u) << 16; return v.f;
}
__device__ __forceinline__ u16 f2bf(float f) {
    union { float f; unsigned int i; } v; v.f = f;
    unsigned int x = v.i;
    return (u16)((x + 0x7FFFu + ((x >> 16) & 1u)) >> 16);
}

__device__ __forceinline__ float ldx(const float* p, int i) { return p[i]; }
__device__ __forceinline__ float ldx(const u16* p, int i) { return bf2f(p[i]); }

__device__ __forceinline__ float wred_sum(float v) {
#pragma unroll
    for (int o = 32; o > 0; o >>= 1) v += __shfl_down(v, o, 64);
    return __shfl(v, 0, 64);
}
__device__ __forceinline__ float wred_max(float v) {
#pragma unroll
    for (int o = 32; o > 0; o >>= 1) v = fmaxf(v, __shfl_down(v, o, 64));
    return __shfl(v, 0, 64);
}

// ---------------- 1. avg-pool along T + concat(+pos, -neg) ----------------
__global__ __launch_bounds__(256)
void pool_kernel(const float* __restrict__ pos, const float* __restrict__ neg,
                 u16* __restrict__ cond) {
    int idx = blockIdx.x * 256 + threadIdx.x;
    const int N = B_ * C_ * TC_ * F_;
    if (idx >= N) return;
    int f  = idx % F_;
    int tc = (idx / F_) % TC_;
    int c  = (idx / (F_ * TC_)) % C_;
    int b  = idx / (F_ * TC_ * C_);
    const float* src; float sign; int t0;
    if (tc < TP_) { src = pos; sign =  1.f; t0 = tc * 5; }
    else          { src = neg; sign = -1.f; t0 = (tc - TP_) * 5; }
    int base = ((b * C_ + c) * T_ + t0) * F_ + f;
    float s = 0.f;
#pragma unroll
    for (int k = 0; k < 10; k++) s += src[base + k * F_];
    cond[idx] = f2bf(s * (sign * 0.1f));
}

// ---------------- 2. Q/K branch: conv1x1(E out/head) + PReLU + LN(E,F) ----
// block per (b,t); thread = (row = h*8+e, oct); f = oct + 8j
template <typename XT>
__global__ __launch_bounds__(256)
void qk_branch_kernel(const XT* __restrict__ x, int Tx,
                      const float* __restrict__ W, const float* __restrict__ bias,
                      const float* __restrict__ alpha,
                      const float* __restrict__ g, const float* __restrict__ bet,
                      u16* __restrict__ out) {
    __shared__ float xs[C_ * F_ + 8];
    int b = blockIdx.x / Tx, t = blockIdx.x % Tx;
    int tid = threadIdx.x;
    int xbase = (b * C_) * Tx * F_ + t * F_;
    for (int i = tid; i < C_ * F_; i += 256) {
        int c = i / F_, f = i % F_;
        xs[i] = ldx(x, xbase + c * Tx * F_ + f);
    }
    if (tid < 8) xs[C_ * F_ + tid] = 0.f;
    __syncthreads();

    int row = tid >> 3;      // h*8 + e
    int oct = tid & 7;
    int h = row >> 3;
    float acc[9];
    float bb = bias[row];
#pragma unroll
    for (int j = 0; j < 9; j++) acc[j] = bb;
    for (int c = 0; c < C_; c++) {
        float w = W[row * C_ + c];
        const float* xr = &xs[c * F_ + oct];
#pragma unroll
        for (int j = 0; j < 9; j++) acc[j] = fmaf(w, xr[8 * j], acc[j]);
    }
    float a = alpha[h];
    float sum = 0.f, ss = 0.f;
#pragma unroll
    for (int j = 0; j < 9; j++) {
        int f = oct + 8 * j;
        if (f < F_) {
            float v = acc[j];
            v = (v >= 0.f) ? v : a * v;
            acc[j] = v;
            sum += v; ss += v * v;
        }
    }
    sum = wred_sum(sum); ss = wred_sum(ss);
    float mu = sum * (1.f / 520.f);
    float var = ss * (1.f / 520.f) - mu * mu;
    float rs = rsqrtf(var + EPS);
    int obase = ((h * B_ + b) * Tx + t) * DQK + (row & 7) * F_;
#pragma unroll
    for (int j = 0; j < 9; j++) {
        int f = oct + 8 * j;
        if (f < F_) {
            float gv = g[row * F_ + f];
            float bv = bet[row * F_ + f];
            out[obase + f] = f2bf((acc[j] - mu) * rs * gv + bv);
        }
    }
}

// ---------------- 3. V branch: conv1x1(32 out/head) + PReLU + LN(Dh,F) ----
// block per (b,t); thread = (row = h*32+dh, half); f = half*33 + j
__global__ __launch_bounds__(256)
void v_branch_kernel(const u16* __restrict__ x,
                     const float* __restrict__ W, const float* __restrict__ bias,
                     const float* __restrict__ alpha,
                     const float* __restrict__ g, const float* __restrict__ bet,
                     u16* __restrict__ out) {
    __shared__ float xs[C_ * F_ + 1];
    int b = blockIdx.x / TC_, t = blockIdx.x % TC_;
    int tid = threadIdx.x;
    int xbase = (b * C_) * TC_ * F_ + t * F_;
    for (int i = tid; i < C_ * F_; i += 256) {
        int c = i / F_, f = i % F_;
        xs[i] = bf2f(x[xbase + c * TC_ * F_ + f]);
    }
    if (tid == 0) xs[C_ * F_] = 0.f;
    __syncthreads();

    int row = tid >> 1;     // h*32 + dh
    int half = tid & 1;
    int h = row >> 5;
    int f0 = half ? 33 : 0;
    float acc[33];
    float bb = bias[row];
#pragma unroll
    for (int j = 0; j < 33; j++) acc[j] = bb;
    for (int c = 0; c < C_; c++) {
        float w = W[row * C_ + c];
        const float* xr = &xs[c * F_ + f0];
#pragma unroll
        for (int j = 0; j < 33; j++) acc[j] = fmaf(w, xr[j], acc[j]);
    }
    float a = alpha[h];
    float sum = 0.f, ss = 0.f;
#pragma unroll
    for (int j = 0; j < 33; j++) {
        if (f0 + j < F_) {
            float v = acc[j];
            v = (v >= 0.f) ? v : a * v;
            acc[j] = v;
            sum += v; ss += v * v;
        }
    }
    sum = wred_sum(sum); ss = wred_sum(ss);
    float mu = sum * (1.f / 2080.f);
    float var = ss * (1.f / 2080.f) - mu * mu;
    float rs = rsqrtf(var + EPS);
    int obase = ((h * B_ + b) * TC_ + t) * DV + (row & 31) * F_ + f0;
#pragma unroll
    for (int j = 0; j < 33; j++) {
        if (f0 + j < F_) {
            float gv = g[row * F_ + f0 + j];
            float bv = bet[row * F_ + f0 + j];
            out[obase + j] = f2bf((acc[j] - mu) * rs * gv + bv);
        }
    }
}

// ---------------- 4. attention: block per (h,b, 8 q rows) ----------------
__global__ __launch_bounds__(256)
void attn_kernel(const u16* __restrict__ Qf, const u16* __restrict__ Kf,
                 const u16* __restrict__ Vf, float* __restrict__ out) {
    __shared__ float qs[8 * DQK];
    __shared__ float p[8 * TC_];
    int tile = blockIdx.x % (T_ / 8);
    int hb = blockIdx.x / (T_ / 8);
    int h = hb / B_, b = hb % B_;
    int tid = threadIdx.x;
    int tq0 = tile * 8;

    int qbase = ((h * B_ + b) * T_ + tq0) * DQK;
    for (int i = tid; i < 8 * DQK; i += 256) qs[i] = bf2f(Qf[qbase + i]);
    __syncthreads();

    const float scale = 0.043852900965f;  // 1/sqrt(520)
    int kbase = (h * B_ + b) * TC_ * DQK;
    for (int idx = tid; idx < 8 * TC_; idx += 256) {
        int s = idx >> 3, q = idx & 7;
        const ushort4* kr = (const ushort4*)&Kf[kbase + s * DQK];
        const float* qr = &qs[q * DQK];
        float acc = 0.f;
        for (int d4 = 0; d4 < DQK / 4; d4++) {
            ushort4 kv = kr[d4];
            int d = d4 * 4;
            acc = fmaf(bf2f(kv.x), qr[d],     acc);
            acc = fmaf(bf2f(kv.y), qr[d + 1], acc);
            acc = fmaf(bf2f(kv.z), qr[d + 2], acc);
            acc = fmaf(bf2f(kv.w), qr[d + 3], acc);
        }
        p[q * TC_ + s] = acc * scale;
    }
    __syncthreads();

    int wave = tid >> 6, lane = tid & 63;
    for (int q = wave * 2; q < wave * 2 + 2; q++) {
        float m = -1e30f;
        for (int s = lane; s < TC_; s += 64) m = fmaxf(m, p[q * TC_ + s]);
        m = wred_max(m);
        float sum = 0.f;
        for (int s = lane; s < TC_; s += 64) {
            float e = __expf(p[q * TC_ + s] - m);
            p[q * TC_ + s] = e; sum += e;
        }
        sum = wred_sum(sum);
        float inv = 1.0f / sum;
        for (int s = lane; s < TC_; s += 64) p[q * TC_ + s] *= inv;
    }
    __syncthreads();

    float acc[9][8];
#pragma unroll
    for (int k = 0; k < 9; k++)
#pragma unroll
        for (int q = 0; q < 8; q++) acc[k][q] = 0.f;

    int vbase = (h * B_ + b) * TC_ * DV;
    for (int s = 0; s < TC_; s++) {
        float pv[8];
#pragma unroll
        for (int q = 0; q < 8; q++) pv[q] = p[q * TC_ + s];
        const u16* vr = &Vf[vbase + s * DV];
#pragma unroll
        for (int k = 0; k < 9; k++) {
            int o = tid + 256 * k;
            if (o < DV) {
                float v = bf2f(vr[o]);
#pragma unroll
                for (int q = 0; q < 8; q++) acc[k][q] = fmaf(pv[q], v, acc[k][q]);
            }
        }
    }
#pragma unroll
    for (int k = 0; k < 9; k++) {
        int o = tid + 256 * k;
        if (o < DV) {
            int dh = o / F_, f = o % F_;
            int c = h * DH_ + dh;
#pragma unroll
            for (int q = 0; q < 8; q++) {
                out[((b * C_ + c) * T_ + (tq0 + q)) * F_ + f] = acc[k][q];
            }
        }
    }
}

// ---------------- 5. projection: conv1x1(C) + PReLU + LN(C,F), in-place ---
__global__ __launch_bounds__(256)
void proj_kernel(float* __restrict__ io,
                 const float* __restrict__ Wp, const float* __restrict__ bp,
                 const float* __restrict__ ap,
                 const float* __restrict__ gp, const float* __restrict__ betp) {
    __shared__ float xs[C_ * F_ + 1];
    __shared__ float wsum[4], wss[4];
    int b = blockIdx.x / T_, t = blockIdx.x % T_;
    int tid = threadIdx.x;
    int xbase = (b * C_) * T_ * F_ + t * F_;
    for (int i = tid; i < C_ * F_; i += 256) {
        int c = i / F_, f = i % F_;
        xs[i] = io[xbase + c * T_ * F_ + f];
    }
    if (tid == 0) xs[C_ * F_] = 0.f;
    __syncthreads();

    int row = tid >> 1;     // e (output channel)
    int half = tid & 1;
    int f0 = half ? 33 : 0;
    float acc[33];
    float bb = bp[row];
#pragma unroll
    for (int j = 0; j < 33; j++) acc[j] = bb;
    for (int c = 0; c < C_; c++) {
        float w = Wp[row * C_ + c];
        const float* xr = &xs[c * F_ + f0];
#pragma unroll
        for (int j = 0; j < 33; j++) acc[j] = fmaf(w, xr[j], acc[j]);
    }
    float a = ap[0];
    float sum = 0.f, ss = 0.f;
#pragma unroll
    for (int j = 0; j < 33; j++) {
        if (f0 + j < F_) {
            float v = acc[j];
            v = (v >= 0.f) ? v : a * v;
            acc[j] = v;
            sum += v; ss += v * v;
        }
    }
    sum = wred_sum(sum); ss = wred_sum(ss);
    int wv = tid >> 6, lane = tid & 63;
    if (lane == 0) { wsum[wv] = sum; wss[wv] = ss; }
    __syncthreads();
    float tsum = wsum[0] + wsum[1] + wsum[2] + wsum[3];
    float tss  = wss[0] + wss[1] + wss[2] + wss[3];
    float mu = tsum * (1.f / 8320.f);
    float var = tss * (1.f / 8320.f) - mu * mu;
    float rs = rsqrtf(var + EPS);
#pragma unroll
    for (int j = 0; j < 33; j++) {
        int f = f0 + j;
        if (f < F_) {
            float gv = gp[row * F_ + f];
            float bv = betp[row * F_ + f];
            io[xbase + row * T_ * F_ + f] = (acc[j] - mu) * rs * gv + bv;
        }
    }
}

extern "C" void kernel_launch(void* const* d_in, const int* in_sizes, int n_in,
                              void* d_out, int out_size, void* d_ws, size_t ws_size,
                              hipStream_t stream) {
    const float* batch = (const float*)d_in[0];
    const float* pos   = (const float*)d_in[1];
    const float* neg   = (const float*)d_in[2];
    const float* WQ   = (const float*)d_in[3];
    const float* bQ   = (const float*)d_in[4];
    const float* aQ   = (const float*)d_in[5];
    const float* gQ   = (const float*)d_in[6];
    const float* betQ = (const float*)d_in[7];
    const float* WK   = (const float*)d_in[8];
    const float* bK   = (const float*)d_in[9];
    const float* aK   = (const float*)d_in[10];
    const float* gK   = (const float*)d_in[11];
    const float* betK = (const float*)d_in[12];
    const float* WV   = (const float*)d_in[13];
    const float* bV   = (const float*)d_in[14];
    const float* aV   = (const float*)d_in[15];
    const float* gV   = (const float*)d_in[16];
    const float* betV = (const float*)d_in[17];
    const float* Wp   = (const float*)d_in[18];
    const float* bp   = (const float*)d_in[19];
    const float* ap   = (const float*)d_in[20];
    const float* gp   = (const float*)d_in[21];
    const float* betp = (const float*)d_in[22];

    char* ws = (char*)d_ws;
    // bf16 intermediates in workspace (total ~76.3 MB)
    u16* cond = (u16*)(ws);                                   // B*C*TC*F   el
    u16* Qf   = (u16*)(ws + 26490880);                        // H*B*T*520  el
    u16* Kf   = (u16*)(ws + 26490880 + 16640000);             // H*B*TC*520 el
    u16* Vf   = (u16*)(ws + 26490880 + 16640000 + 6622720);   // H*B*TC*2080 el
    float* o  = (float*)d_out;

    const int NPOOL = B_ * C_ * TC_ * F_;
    pool_kernel<<<(NPOOL + 255) / 256, 256, 0, stream>>>(pos, neg, cond);
    qk_branch_kernel<float><<<B_ * T_,  256, 0, stream>>>(batch, T_,  WQ, bQ, aQ, gQ, betQ, Qf);
    qk_branch_kernel<u16>  <<<B_ * TC_, 256, 0, stream>>>(cond,  TC_, WK, bK, aK, gK, betK, Kf);
    v_branch_kernel <<<B_ * TC_, 256, 0, stream>>>(cond, WV, bV, aV, gV, betV, Vf);
    attn_kernel<<<H_ * B_ * (T_ / 8), 256, 0, stream>>>(Qf, Kf, Vf, o);
    proj_kernel<<<B_ * T_, 256, 0, stream>>>(o, Wp, bp, ap, gp, betp);
}

// Round 3
// 1200.452 us; speedup vs baseline: 1.7771x; 1.7771x over previous
//
#include <hip/hip_runtime.h>
#include <hip/hip_bf16.h>

typedef unsigned short u16;
typedef __attribute__((ext_vector_type(8))) short bfrag;   // 8 bf16 = 4 VGPR
typedef __attribute__((ext_vector_type(4))) float f32x4;

#define B_ 4
#define C_ 128
#define T_ 1000
#define F_ 65
#define H_ 4
#define E_ 8
#define DH_ 32
#define TP_ 199
#define TC_ 398
#define DQK 520      // E*F
#define DQKP 544     // padded K-dim for MFMA (17 chunks of 32)
#define DV 2080      // DH*F
#define SP_ 416      // padded s (26 tiles of 16, 13 chunks of 32)
#define QROWS 1008   // padded T rows (63 tiles of 16)
#define EPS 1e-5f

__device__ __forceinline__ float bf2f(u16 u) {
    union { float f; unsigned int i; } v; v.i = ((unsigned int)u) << 16; return v.f;
}
__device__ __forceinline__ u16 f2bf(float f) {
    union { float f; unsigned int i; } v; v.f = f;
    unsigned int x = v.i;
    return (u16)((x + 0x7FFFu + ((x >> 16) & 1u)) >> 16);
}

__device__ __forceinline__ float ldx(const float* p, int i) { return p[i]; }
__device__ __forceinline__ float ldx(const u16* p, int i) { return bf2f(p[i]); }

__device__ __forceinline__ float wred_sum(float v) {
#pragma unroll
    for (int o = 32; o > 0; o >>= 1) v += __shfl_down(v, o, 64);
    return __shfl(v, 0, 64);
}

// ---------------- 1. avg-pool along T + concat(+pos, -neg) ----------------
__global__ __launch_bounds__(256)
void pool_kernel(const float* __restrict__ pos, const float* __restrict__ neg,
                 u16* __restrict__ cond) {
    int idx = blockIdx.x * 256 + threadIdx.x;
    const int N = B_ * C_ * TC_ * F_;
    if (idx >= N) return;
    int f  = idx % F_;
    int tc = (idx / F_) % TC_;
    int c  = (idx / (F_ * TC_)) % C_;
    int b  = idx / (F_ * TC_ * C_);
    const float* src; float sign; int t0;
    if (tc < TP_) { src = pos; sign =  1.f; t0 = tc * 5; }
    else          { src = neg; sign = -1.f; t0 = (tc - TP_) * 5; }
    int base = ((b * C_ + c) * T_ + t0) * F_ + f;
    float s = 0.f;
#pragma unroll
    for (int k = 0; k < 10; k++) s += src[base + k * F_];
    cond[idx] = f2bf(s * (sign * 0.1f));
}

// ---------------- 2. Q/K branch: conv1x1 + PReLU + LN(E,F) ----------------
// block per (b,t); thread = (row = h*8+e, oct); f = oct + 8j
// writes rows of length `ldout` (Q: 520, K: 544-padded), `rowsper` rows per (h,b)
template <typename XT>
__global__ __launch_bounds__(256)
void qk_branch_kernel(const XT* __restrict__ x, int Tx, int rowsper, int ldout,
                      const float* __restrict__ W, const float* __restrict__ bias,
                      const float* __restrict__ alpha,
                      const float* __restrict__ g, const float* __restrict__ bet,
                      u16* __restrict__ out) {
    __shared__ float xs[C_ * F_ + 8];
    int b = blockIdx.x / Tx, t = blockIdx.x % Tx;
    int tid = threadIdx.x;
    int xbase = (b * C_) * Tx * F_ + t * F_;
    for (int i = tid; i < C_ * F_; i += 256) {
        int c = i / F_, f = i % F_;
        xs[i] = ldx(x, xbase + c * Tx * F_ + f);
    }
    if (tid < 8) xs[C_ * F_ + tid] = 0.f;
    __syncthreads();

    int row = tid >> 3;      // h*8 + e
    int oct = tid & 7;
    int h = row >> 3;
    float acc[9];
    float bb = bias[row];
#pragma unroll
    for (int j = 0; j < 9; j++) acc[j] = bb;
    for (int c = 0; c < C_; c++) {
        float w = W[row * C_ + c];
        const float* xr = &xs[c * F_ + oct];
#pragma unroll
        for (int j = 0; j < 9; j++) acc[j] = fmaf(w, xr[8 * j], acc[j]);
    }
    float a = alpha[h];
    float sum = 0.f, ss = 0.f;
#pragma unroll
    for (int j = 0; j < 9; j++) {
        int f = oct + 8 * j;
        if (f < F_) {
            float v = acc[j];
            v = (v >= 0.f) ? v : a * v;
            acc[j] = v;
            sum += v; ss += v * v;
        }
    }
    sum = wred_sum(sum); ss = wred_sum(ss);
    float mu = sum * (1.f / 520.f);
    float var = ss * (1.f / 520.f) - mu * mu;
    float rs = rsqrtf(var + EPS);
    size_t obase = (size_t)((h * B_ + b) * rowsper + t) * ldout + (row & 7) * F_;
#pragma unroll
    for (int j = 0; j < 9; j++) {
        int f = oct + 8 * j;
        if (f < F_) {
            float gv = g[row * F_ + f];
            float bv = bet[row * F_ + f];
            out[obase + f] = f2bf((acc[j] - mu) * rs * gv + bv);
        }
    }
}

// ---------------- 3. V branch: conv1x1(32 out/head) + PReLU + LN(Dh,F) ----
__global__ __launch_bounds__(256)
void v_branch_kernel(const u16* __restrict__ x,
                     const float* __restrict__ W, const float* __restrict__ bias,
                     const float* __restrict__ alpha,
                     const float* __restrict__ g, const float* __restrict__ bet,
                     u16* __restrict__ out) {
    __shared__ float xs[C_ * F_ + 1];
    int b = blockIdx.x / TC_, t = blockIdx.x % TC_;
    int tid = threadIdx.x;
    int xbase = (b * C_) * TC_ * F_ + t * F_;
    for (int i = tid; i < C_ * F_; i += 256) {
        int c = i / F_, f = i % F_;
        xs[i] = bf2f(x[xbase + c * TC_ * F_ + f]);
    }
    if (tid == 0) xs[C_ * F_] = 0.f;
    __syncthreads();

    int row = tid >> 1;     // h*32 + dh
    int half = tid & 1;
    int h = row >> 5;
    int f0 = half ? 33 : 0;
    float acc[33];
    float bb = bias[row];
#pragma unroll
    for (int j = 0; j < 33; j++) acc[j] = bb;
    for (int c = 0; c < C_; c++) {
        float w = W[row * C_ + c];
        const float* xr = &xs[c * F_ + f0];
#pragma unroll
        for (int j = 0; j < 33; j++) acc[j] = fmaf(w, xr[j], acc[j]);
    }
    float a = alpha[h];
    float sum = 0.f, ss = 0.f;
#pragma unroll
    for (int j = 0; j < 33; j++) {
        if (f0 + j < F_) {
            float v = acc[j];
            v = (v >= 0.f) ? v : a * v;
            acc[j] = v;
            sum += v; ss += v * v;
        }
    }
    sum = wred_sum(sum); ss = wred_sum(ss);
    float mu = sum * (1.f / 2080.f);
    float var = ss * (1.f / 2080.f) - mu * mu;
    float rs = rsqrtf(var + EPS);
    size_t obase = (size_t)((h * B_ + b) * TC_ + t) * DV + (row & 31) * F_ + f0;
#pragma unroll
    for (int j = 0; j < 33; j++) {
        if (f0 + j < F_) {
            float gv = g[row * F_ + f0 + j];
            float bv = bet[row * F_ + f0 + j];
            out[obase + j] = f2bf((acc[j] - mu) * rs * gv + bv);
        }
    }
}

// ---------------- 3b. transpose V: [s][e] -> [e][s] (s padded 416, zeros) --
__global__ __launch_bounds__(256)
void transpose_v_kernel(const u16* __restrict__ Vf, u16* __restrict__ Vt) {
    __shared__ u16 tileb[32][33];
    int id = blockIdx.x;
    int sb = id % 13; id /= 13;
    int eb = id % 65; int hb = id / 65;
    const u16* src = Vf + (size_t)hb * TC_ * DV;
    u16* dst = Vt + (size_t)hb * DV * SP_;
    int j = threadIdx.x & 31, i0 = threadIdx.x >> 5;
#pragma unroll
    for (int k = 0; k < 4; k++) {
        int i = i0 + 8 * k;                 // s-local
        int s = sb * 32 + i, e = eb * 32 + j;
        u16 v = 0;
        if (s < TC_) v = src[(size_t)s * DV + e];
        tileb[i][j] = v;
    }
    __syncthreads();
#pragma unroll
    for (int k = 0; k < 4; k++) {
        int i2 = i0 + 8 * k;                // e-local
        int e = eb * 32 + i2, s = sb * 32 + j;
        dst[(size_t)e * SP_ + s] = tileb[j][i2];
    }
}

// ---------------- 4. MFMA attention: block per (h,b, 16 q rows) -----------
// QK^T in-register (C-layout), shuffle softmax, P->LDS bf16, PV as O^T=V^T.P^T
__global__ __launch_bounds__(256, 4)
void attn_kernel(const u16* __restrict__ Qf, const u16* __restrict__ Kf,
                 const u16* __restrict__ Vt, float* __restrict__ out) {
    __shared__ u16 qlds[16 * 552];          // Q tile, K-dim padded 544 (+8 bank pad)
    __shared__ u16 plds[16 * 424];          // P tile, s padded 416 (+8 bank pad)
    __shared__ float redmax[16 * 4];
    __shared__ float redsum[16 * 4];

    int tile = blockIdx.x % 63;
    int hb   = blockIdx.x / 63;             // h*4 + b
    int h = hb >> 2, b = hb & 3;
    int tid = threadIdx.x;
    int wave = tid >> 6, lane = tid & 63;
    int g = lane >> 4;                      // k-group (0..3)
    int n = lane & 15;
    int tq0 = tile * 16;

    // ---- stage Q tile into LDS (16 x 552, cols >=520 zero) ----
    const u16* qbase = Qf + (size_t)(hb * QROWS + tq0) * DQK;
    for (int i = tid; i < 16 * 69; i += 256) {
        int q = i / 69, cb = i % 69;
        uint4 val = make_uint4(0, 0, 0, 0);
        if (cb < 65) val = *(const uint4*)(qbase + (size_t)q * DQK + cb * 8);
        *(uint4*)(&qlds[q * 552 + cb * 8]) = val;
    }
    __syncthreads();

    // ---- QK^T: wave handles s-tiles tau = wave + 4i (tau < 26) ----
    f32x4 acc[7];
#pragma unroll
    for (int i = 0; i < 7; i++) acc[i] = (f32x4){0.f, 0.f, 0.f, 0.f};
    const u16* kslab = Kf + (size_t)hb * SP_ * DQKP;
    for (int c = 0; c < 17; c++) {
        bfrag aq = *(const bfrag*)(&qlds[n * 552 + c * 32 + g * 8]);
#pragma unroll
        for (int i = 0; i < 7; i++) {
            int tau = wave + 4 * i;
            if (tau < 26) {
                bfrag bk = *(const bfrag*)(kslab + (size_t)(tau * 16 + n) * DQKP + c * 32 + g * 8);
                acc[i] = __builtin_amdgcn_mfma_f32_16x16x32_bf16(aq, bk, acc[i], 0, 0, 0);
            }
        }
    }

    // ---- softmax over s (rows q = g*4+r live across 16-lane group + 4 waves)
    const float scale = 0.043852900965f;    // 1/sqrt(520)
    float m4[4], s4[4];
#pragma unroll
    for (int r = 0; r < 4; r++) {
        float mx = -1e30f;
#pragma unroll
        for (int i = 0; i < 7; i++) {
            int tau = wave + 4 * i;
            int s = tau * 16 + n;
            if (tau < 26 && s < TC_) mx = fmaxf(mx, acc[i][r] * scale);
        }
        mx = fmaxf(mx, __shfl_xor(mx, 1, 64));
        mx = fmaxf(mx, __shfl_xor(mx, 2, 64));
        mx = fmaxf(mx, __shfl_xor(mx, 4, 64));
        mx = fmaxf(mx, __shfl_xor(mx, 8, 64));
        m4[r] = mx;
    }
    if (n == 0) {
#pragma unroll
        for (int r = 0; r < 4; r++) redmax[(g * 4 + r) * 4 + wave] = m4[r];
    }
    __syncthreads();
#pragma unroll
    for (int r = 0; r < 4; r++) {
        int q = g * 4 + r;
        m4[r] = fmaxf(fmaxf(redmax[q * 4 + 0], redmax[q * 4 + 1]),
                      fmaxf(redmax[q * 4 + 2], redmax[q * 4 + 3]));
        s4[r] = 0.f;
    }
#pragma unroll
    for (int i = 0; i < 7; i++) {
        int tau = wave + 4 * i;
        if (tau < 26) {
            int s = tau * 16 + n;
#pragma unroll
            for (int r = 0; r < 4; r++) {
                float e = (s < TC_) ? __expf(acc[i][r] * scale - m4[r]) : 0.f;
                acc[i][r] = e;
                s4[r] += e;
            }
        }
    }
#pragma unroll
    for (int r = 0; r < 4; r++) {
        float sm = s4[r];
        sm += __shfl_xor(sm, 1, 64);
        sm += __shfl_xor(sm, 2, 64);
        sm += __shfl_xor(sm, 4, 64);
        sm += __shfl_xor(sm, 8, 64);
        s4[r] = sm;
    }
    if (n == 0) {
#pragma unroll
        for (int r = 0; r < 4; r++) redsum[(g * 4 + r) * 4 + wave] = s4[r];
    }
    __syncthreads();
#pragma unroll
    for (int r = 0; r < 4; r++) {
        int q = g * 4 + r;
        float tot = redsum[q * 4 + 0] + redsum[q * 4 + 1] + redsum[q * 4 + 2] + redsum[q * 4 + 3];
        s4[r] = 1.0f / tot;
    }
    // write P (bf16) to LDS: rows q, cols s (all 416 cols covered by tiles 0..25)
#pragma unroll
    for (int i = 0; i < 7; i++) {
        int tau = wave + 4 * i;
        if (tau < 26) {
            int s = tau * 16 + n;
#pragma unroll
            for (int r = 0; r < 4; r++) {
                plds[(g * 4 + r) * 424 + s] = f2bf(acc[i][r] * s4[r]);
            }
        }
    }
    __syncthreads();

    // ---- PV: O^T = V^T . P^T ; B-frags (P) preloaded, dv-tiles in pairs ----
    bfrag bp[13];
#pragma unroll
    for (int c = 0; c < 13; c++)
        bp[c] = *(const bfrag*)(&plds[n * 424 + c * 32 + g * 8]);

    const u16* vslab = Vt + (size_t)hb * DV * SP_;
    int t = tq0 + n;                        // output time index (col = q = n)
    for (int j = 0; j < 17; j++) {
        int p = wave + 4 * j;               // dv-pair index (wave-uniform)
        if (p >= 65) break;
        int e0 = p * 32;
        f32x4 a0 = (f32x4){0.f, 0.f, 0.f, 0.f};
        f32x4 a1 = (f32x4){0.f, 0.f, 0.f, 0.f};
#pragma unroll
        for (int c = 0; c < 13; c++) {
            bfrag v0 = *(const bfrag*)(vslab + (size_t)(e0 + n) * SP_ + c * 32 + g * 8);
            bfrag v1 = *(const bfrag*)(vslab + (size_t)(e0 + 16 + n) * SP_ + c * 32 + g * 8);
            a0 = __builtin_amdgcn_mfma_f32_16x16x32_bf16(v0, bp[c], a0, 0, 0, 0);
            a1 = __builtin_amdgcn_mfma_f32_16x16x32_bf16(v1, bp[c], a1, 0, 0, 0);
        }
        if (t < T_) {
#pragma unroll
            for (int r = 0; r < 4; r++) {
                int e = e0 + g * 4 + r;     // tile0 row
                int dh = e / F_, f = e - dh * F_;
                out[((size_t)(b * C_ + h * DH_ + dh) * T_ + t) * F_ + f] = a0[r];
                int e2 = e0 + 16 + g * 4 + r;
                int dh2 = e2 / F_, f2 = e2 - dh2 * F_;
                out[((size_t)(b * C_ + h * DH_ + dh2) * T_ + t) * F_ + f2] = a1[r];
            }
        }
    }
}

// ---------------- 5. projection: conv1x1(C) + PReLU + LN(C,F), in-place ---
__global__ __launch_bounds__(256)
void proj_kernel(float* __restrict__ io,
                 const float* __restrict__ Wp, const float* __restrict__ bp,
                 const float* __restrict__ ap,
                 const float* __restrict__ gp, const float* __restrict__ betp) {
    __shared__ float xs[C_ * F_ + 1];
    __shared__ float wsum[4], wss[4];
    int b = blockIdx.x / T_, t = blockIdx.x % T_;
    int tid = threadIdx.x;
    int xbase = (b * C_) * T_ * F_ + t * F_;
    for (int i = tid; i < C_ * F_; i += 256) {
        int c = i / F_, f = i % F_;
        xs[i] = io[xbase + c * T_ * F_ + f];
    }
    if (tid == 0) xs[C_ * F_] = 0.f;
    __syncthreads();

    int row = tid >> 1;
    int half = tid & 1;
    int f0 = half ? 33 : 0;
    float acc[33];
    float bb = bp[row];
#pragma unroll
    for (int j = 0; j < 33; j++) acc[j] = bb;
    for (int c = 0; c < C_; c++) {
        float w = Wp[row * C_ + c];
        const float* xr = &xs[c * F_ + f0];
#pragma unroll
        for (int j = 0; j < 33; j++) acc[j] = fmaf(w, xr[j], acc[j]);
    }
    float a = ap[0];
    float sum = 0.f, ss = 0.f;
#pragma unroll
    for (int j = 0; j < 33; j++) {
        if (f0 + j < F_) {
            float v = acc[j];
            v = (v >= 0.f) ? v : a * v;
            acc[j] = v;
            sum += v; ss += v * v;
        }
    }
    sum = wred_sum(sum); ss = wred_sum(ss);
    int wv = tid >> 6, lane = tid & 63;
    if (lane == 0) { wsum[wv] = sum; wss[wv] = ss; }
    __syncthreads();
    float tsum = wsum[0] + wsum[1] + wsum[2] + wsum[3];
    float tss  = wss[0] + wss[1] + wss[2] + wss[3];
    float mu = tsum * (1.f / 8320.f);
    float var = tss * (1.f / 8320.f) - mu * mu;
    float rs = rsqrtf(var + EPS);
#pragma unroll
    for (int j = 0; j < 33; j++) {
        int f = f0 + j;
        if (f < F_) {
            float gv = gp[row * F_ + f];
            float bv = betp[row * F_ + f];
            io[xbase + row * T_ * F_ + f] = (acc[j] - mu) * rs * gv + bv;
        }
    }
}

extern "C" void kernel_launch(void* const* d_in, const int* in_sizes, int n_in,
                              void* d_out, int out_size, void* d_ws, size_t ws_size,
                              hipStream_t stream) {
    const float* batch = (const float*)d_in[0];
    const float* pos   = (const float*)d_in[1];
    const float* neg   = (const float*)d_in[2];
    const float* WQ   = (const float*)d_in[3];
    const float* bQ   = (const float*)d_in[4];
    const float* aQ   = (const float*)d_in[5];
    const float* gQ   = (const float*)d_in[6];
    const float* betQ = (const float*)d_in[7];
    const float* WK   = (const float*)d_in[8];
    const float* bK   = (const float*)d_in[9];
    const float* aK   = (const float*)d_in[10];
    const float* gK   = (const float*)d_in[11];
    const float* betK = (const float*)d_in[12];
    const float* WV   = (const float*)d_in[13];
    const float* bV   = (const float*)d_in[14];
    const float* aV   = (const float*)d_in[15];
    const float* gV   = (const float*)d_in[16];
    const float* betV = (const float*)d_in[17];
    const float* Wp   = (const float*)d_in[18];
    const float* bp   = (const float*)d_in[19];
    const float* ap   = (const float*)d_in[20];
    const float* gp   = (const float*)d_in[21];
    const float* betp = (const float*)d_in[22];

    char* ws = (char*)d_ws;
    // layout (cond aliases Vt; cond is dead before transpose writes Vt):
    //   Vt   [0, 27,688,960)          16*2080*416*2
    //   Qf   [27,688,960, 44,462,080) 16*1008*520*2
    //   Kf   [44,462,080, 51,703,808) 16*416*544*2
    //   Vf   [51,703,808, 78,194,688) 16*398*2080*2
    u16* Vt   = (u16*)(ws);
    u16* cond = (u16*)(ws);
    u16* Qf   = (u16*)(ws + 27688960);
    u16* Kf   = (u16*)(ws + 44462080);
    u16* Vf   = (u16*)(ws + 51703808);
    float* o  = (float*)d_out;

    const int NPOOL = B_ * C_ * TC_ * F_;
    pool_kernel<<<(NPOOL + 255) / 256, 256, 0, stream>>>(pos, neg, cond);
    qk_branch_kernel<float><<<B_ * T_,  256, 0, stream>>>(batch, T_,  QROWS, DQK,  WQ, bQ, aQ, gQ, betQ, Qf);
    qk_branch_kernel<u16>  <<<B_ * TC_, 256, 0, stream>>>(cond,  TC_, SP_,   DQKP, WK, bK, aK, gK, betK, Kf);
    v_branch_kernel <<<B_ * TC_, 256, 0, stream>>>(cond, WV, bV, aV, gV, betV, Vf);
    transpose_v_kernel<<<16 * 65 * 13, 256, 0, stream>>>(Vf, Vt);
    attn_kernel<<<16 * 63, 256, 0, stream>>>(Qf, Kf, Vt, o);
    proj_kernel<<<B_ * T_, 256, 0, stream>>>(o, Wp, bp, ap, gp, betp);
}